// Round 2
// baseline (594.383 us; speedup 1.0000x reference)
//
#include <hip/hip_runtime.h>
#include <hip/hip_bf16.h>

typedef unsigned short ushort_t;
typedef unsigned int   uint_t;

typedef short    frag8  __attribute__((ext_vector_type(8)));   // 8 bf16 (4 VGPRs)
typedef float    f32x4  __attribute__((ext_vector_type(4)));
typedef ushort_t u16x8  __attribute__((ext_vector_type(8)));
typedef ushort_t u16x4  __attribute__((ext_vector_type(4)));

#define LOG2E 1.44269504088896340736f

constexpr int B_ = 4;
constexpr int C_ = 512;
constexpr int N_ = 4096;
constexpr int D_ = 64;    // CQK
constexpr int OROWS = 640; // 64 q + 64 k + 512 v

__device__ __forceinline__ ushort_t f2bf(float f) {
    unsigned int x = __float_as_uint(f);
    unsigned int r = x + 0x7fffu + ((x >> 16) & 1u);
    return (ushort_t)(r >> 16);
}
__device__ __forceinline__ float bf2f(ushort_t h) {
    return __uint_as_float(((uint_t)h) << 16);
}

// ---------------- kernel 0: pack weights to bf16 hi (+ lo residual for q/k rows)
// rows: [wq(64); wk(64); wv(512)] x 512
__global__ __launch_bounds__(256) void convw(const float* __restrict__ wq,
                                             const float* __restrict__ wk,
                                             const float* __restrict__ wv,
                                             ushort_t* __restrict__ Wb,
                                             ushort_t* __restrict__ Wlo) {
    int idx = (blockIdx.x * 256 + threadIdx.x) * 4;
    int row = idx >> 9, col = idx & 511;
    const float* src = (row < 64)  ? wq + (size_t)row * 512 + col
                     : (row < 128) ? wk + (size_t)(row - 64) * 512 + col
                                   : wv + (size_t)(row - 128) * 512 + col;
    float4 v = *(const float4*)src;
    float f[4] = {v.x, v.y, v.z, v.w};
    u16x4 o, ol;
#pragma unroll
    for (int e = 0; e < 4; e++) {
        o[e] = f2bf(f[e]);
        ol[e] = f2bf(f[e] - bf2f(o[e]));
    }
    *(u16x4*)(Wb + idx) = o;
    if (row < 128) *(u16x4*)(Wlo + idx) = ol;
}

// ---------------- kernel 1: xT[b][n][c] bf16 hi + lo (transpose of x[b][c][n])
__global__ __launch_bounds__(256) void xpose(const float* __restrict__ x,
                                             ushort_t* __restrict__ xT,
                                             ushort_t* __restrict__ xTlo) {
    __shared__ float lds[64][65];
    const int b = blockIdx.z, c0 = blockIdx.y * 64, n0 = blockIdx.x * 64;
    const int t = threadIdx.x;
    const float* xb = x + (size_t)b * C_ * N_;
#pragma unroll
    for (int i = 0; i < 16; i++) {
        int e = t + i * 256, cc = e >> 6, nn = e & 63;
        lds[cc][nn] = xb[(size_t)(c0 + cc) * N_ + n0 + nn];
    }
    __syncthreads();
    size_t dsto = ((size_t)b * N_ + n0) * C_ + c0;
#pragma unroll
    for (int i = 0; i < 2; i++) {
        int g = t + i * 256, nn = g >> 3, c8 = (g & 7) * 8;
        u16x8 o, ol;
#pragma unroll
        for (int e = 0; e < 8; e++) {
            float f = lds[c8 + e][nn];
            o[e] = f2bf(f);
            ol[e] = f2bf(f - bf2f(o[e]));
        }
        *(u16x8*)(xT + dsto + (size_t)nn * C_ + c8) = o;
        *(u16x8*)(xTlo + dsto + (size_t)nn * C_ + c8) = ol;
    }
}

// ---------------- kernel 2: projections via MFMA.
// D[m=o][n=npos] = sum_c W[o][c] * xT[n][c]; A=W rows, B=xT rows (both k-contig).
// q/k rows (orow<128): 3-term split-precision; v rows: single bf16.
__global__ __launch_bounds__(256) void proj(const ushort_t* __restrict__ Wb,
                                            const ushort_t* __restrict__ Wlo,
                                            const ushort_t* __restrict__ xT,
                                            const ushort_t* __restrict__ xTlo,
                                            const float* __restrict__ bq,
                                            const float* __restrict__ bk,
                                            const float* __restrict__ bv,
                                            ushort_t* __restrict__ Qt,
                                            ushort_t* __restrict__ Qlo,
                                            ushort_t* __restrict__ Kt,
                                            ushort_t* __restrict__ Klo,
                                            ushort_t* __restrict__ Vb) {
    const int b = blockIdx.z, oy = blockIdx.y, nx = blockIdx.x;
    const int t = threadIdx.x, w = t >> 6, lane = t & 63, lo = lane & 15, hi = lane >> 4;
    const int orow = oy * 64 + w * 16;   // 0..639
    const int n0 = nx * 64;
    const ushort_t* ap = Wb + (size_t)(orow + lo) * 512 + hi * 8;
    const size_t bpo = ((size_t)b * N_ + n0 + lo) * C_ + hi * 8;
    f32x4 acc[4] = {};
    if (orow < 128) {
        const ushort_t* apl = Wlo + (size_t)(orow + lo) * 512 + hi * 8;
        for (int c = 0; c < C_; c += 32) {
            frag8 a  = *(const frag8*)(ap + c);
            frag8 al = *(const frag8*)(apl + c);
#pragma unroll
            for (int nt = 0; nt < 4; nt++) {
                frag8 bb = *(const frag8*)(xT + bpo + (size_t)nt * 16 * C_ + c);
                frag8 bl = *(const frag8*)(xTlo + bpo + (size_t)nt * 16 * C_ + c);
                acc[nt] = __builtin_amdgcn_mfma_f32_16x16x32_bf16(a, bb, acc[nt], 0, 0, 0);
                acc[nt] = __builtin_amdgcn_mfma_f32_16x16x32_bf16(al, bb, acc[nt], 0, 0, 0);
                acc[nt] = __builtin_amdgcn_mfma_f32_16x16x32_bf16(a, bl, acc[nt], 0, 0, 0);
            }
        }
    } else {
        for (int c = 0; c < C_; c += 32) {
            frag8 a = *(const frag8*)(ap + c);
#pragma unroll
            for (int nt = 0; nt < 4; nt++) {
                frag8 bb = *(const frag8*)(xT + bpo + (size_t)nt * 16 * C_ + c);
                acc[nt] = __builtin_amdgcn_mfma_f32_16x16x32_bf16(a, bb, acc[nt], 0, 0, 0);
            }
        }
    }
    float bias[4];
#pragma unroll
    for (int r = 0; r < 4; r++) {
        int o = orow + hi * 4 + r;
        bias[r] = (o < 64) ? bq[o] : (o < 128) ? bk[o - 64] : bv[o - 128];
    }
    if (orow < 128) {
        // q/k -> transposed layout [b][n][64] hi + lo, pack bf16 pairs along o
        ushort_t* dsth = (orow < 64 ? Qt : Kt);
        ushort_t* dstl = (orow < 64 ? Qlo : Klo);
        int ob = (orow & 63) + hi * 4;
#pragma unroll
        for (int nt = 0; nt < 4; nt++) {
            int n = n0 + nt * 16 + lo;
            ushort_t h[4], l[4];
#pragma unroll
            for (int r = 0; r < 4; r++) {
                float f = acc[nt][r] + bias[r];
                h[r] = f2bf(f);
                l[r] = f2bf(f - bf2f(h[r]));
            }
            size_t doff = ((size_t)b * N_ + n) * D_ + ob;
            uint_t* dph = (uint_t*)(dsth + doff);
            dph[0] = (uint_t)h[0] | ((uint_t)h[1] << 16);
            dph[1] = (uint_t)h[2] | ((uint_t)h[3] << 16);
            uint_t* dpl = (uint_t*)(dstl + doff);
            dpl[0] = (uint_t)l[0] | ((uint_t)l[1] << 16);
            dpl[1] = (uint_t)l[2] | ((uint_t)l[3] << 16);
        }
    } else {
        int c0 = orow - 128 + hi * 4;
#pragma unroll
        for (int nt = 0; nt < 4; nt++) {
            int n = n0 + nt * 16 + lo;
#pragma unroll
            for (int r = 0; r < 4; r++)
                Vb[((size_t)b * C_ + c0 + r) * N_ + n] = f2bf(acc[nt][r] + bias[r]);
        }
    }
}

// ---------------- kernel 3: softmax stats (m in log2-domain, inv-sum), online over j
__global__ __launch_bounds__(256) void attn_stats(const ushort_t* __restrict__ Qt,
                                                  const ushort_t* __restrict__ Qlo,
                                                  const ushort_t* __restrict__ Kt,
                                                  const ushort_t* __restrict__ Klo,
                                                  float* __restrict__ m2,
                                                  float* __restrict__ li) {
    const int b = blockIdx.y, i0 = blockIdx.x * 64;
    const int t = threadIdx.x, w = t >> 6, lane = t & 63, lo = lane & 15, hi = lane >> 4;
    const size_t qoff = ((size_t)b * N_ + i0 + w * 16 + lo) * D_ + hi * 8;
    frag8 qh0 = *(const frag8*)(Qt + qoff);
    frag8 qh1 = *(const frag8*)(Qt + qoff + 32);
    frag8 ql0 = *(const frag8*)(Qlo + qoff);
    frag8 ql1 = *(const frag8*)(Qlo + qoff + 32);
    float m[4] = {-INFINITY, -INFINITY, -INFINITY, -INFINITY};
    float l[4] = {0.f, 0.f, 0.f, 0.f};
    for (int jb = 0; jb < N_; jb += 64) {
#pragma unroll
        for (int u = 0; u < 4; u++) {
            const size_t koff = ((size_t)b * N_ + jb + u * 16 + lo) * D_ + hi * 8;
            frag8 kh0 = *(const frag8*)(Kt + koff);
            frag8 kh1 = *(const frag8*)(Kt + koff + 32);
            frag8 kl0 = *(const frag8*)(Klo + koff);
            frag8 kl1 = *(const frag8*)(Klo + koff + 32);
            f32x4 s = {0.f, 0.f, 0.f, 0.f};
            s = __builtin_amdgcn_mfma_f32_16x16x32_bf16(qh0, kh0, s, 0, 0, 0);
            s = __builtin_amdgcn_mfma_f32_16x16x32_bf16(qh1, kh1, s, 0, 0, 0);
            s = __builtin_amdgcn_mfma_f32_16x16x32_bf16(ql0, kh0, s, 0, 0, 0);
            s = __builtin_amdgcn_mfma_f32_16x16x32_bf16(ql1, kh1, s, 0, 0, 0);
            s = __builtin_amdgcn_mfma_f32_16x16x32_bf16(qh0, kl0, s, 0, 0, 0);
            s = __builtin_amdgcn_mfma_f32_16x16x32_bf16(qh1, kl1, s, 0, 0, 0);
#pragma unroll
            for (int r = 0; r < 4; r++) {
                float s2 = s[r] * LOG2E;
                float mn = fmaxf(m[r], s2);
                l[r] = l[r] * exp2f(m[r] - mn) + exp2f(s2 - mn);
                m[r] = mn;
            }
        }
    }
    // merge the 16 j-subsets (across lanes differing in low 4 bits)
#pragma unroll
    for (int off = 1; off < 16; off <<= 1) {
#pragma unroll
        for (int r = 0; r < 4; r++) {
            float om = __shfl_xor(m[r], off);
            float ol = __shfl_xor(l[r], off);
            float mn = fmaxf(m[r], om);
            l[r] = l[r] * exp2f(m[r] - mn) + ol * exp2f(om - mn);
            m[r] = mn;
        }
    }
    if (lo == 0) {
#pragma unroll
        for (int r = 0; r < 4; r++) {
            int i = i0 + w * 16 + hi * 4 + r;
            m2[b * N_ + i] = m[r];
            li[b * N_ + i] = 1.0f / l[r];
        }
    }
}

// ---------------- kernel 4: output. Block = 64 i-rows x full C. 8 waves.
// St = mfma(K,Q) (split-precision) -> P_lds[i][j]; out^T[i][c] = mfma(P, V).
__global__ __launch_bounds__(512) void attn_out(const ushort_t* __restrict__ Qt,
                                                const ushort_t* __restrict__ Qlo,
                                                const ushort_t* __restrict__ Kt,
                                                const ushort_t* __restrict__ Klo,
                                                const ushort_t* __restrict__ Vb,
                                                const float* __restrict__ m2,
                                                const float* __restrict__ li,
                                                float* __restrict__ out) {
    __shared__ ushort_t Plds[64][72];   // [i][j], 144B stride: balanced 16B-slot classes
    // XCD-aware swizzle: batch b -> XCDs {2b,2b+1} so V[b] (4MB) stays L2-resident
    const int bid = blockIdx.x;
    const int xcd = bid & 7;
    const int b = xcd >> 1;
    const int i0 = ((bid >> 3) * 2 + (xcd & 1)) * 64;
    const int t = threadIdx.x, w = t >> 6, lane = t & 63, lo = lane & 15, hi = lane >> 4;
    const int jt = w >> 1;          // this wave's St j-tile (0..3)
    const int itb = (w & 1) * 2;    // this wave's St i-tile base (0 or 2)

    frag8 qfh[2][2], qfl[2][2];
    float mv[2], lv[2];
#pragma unroll
    for (int q = 0; q < 2; q++) {
        const int i = i0 + (itb + q) * 16 + lo;
        const size_t qoff = ((size_t)b * N_ + i) * D_ + hi * 8;
        qfh[q][0] = *(const frag8*)(Qt + qoff);
        qfh[q][1] = *(const frag8*)(Qt + qoff + 32);
        qfl[q][0] = *(const frag8*)(Qlo + qoff);
        qfl[q][1] = *(const frag8*)(Qlo + qoff + 32);
        mv[q] = m2[b * N_ + i];
        lv[q] = li[b * N_ + i];
    }

    f32x4 acc[4][4] = {};   // [it][ct]; c = w*64 + ct*16 + lo
    const ushort_t* Vbase = Vb + ((size_t)b * C_ + w * 64 + lo) * N_;

    for (int jb = 0; jb < N_; jb += 64) {
        const size_t koff = ((size_t)b * N_ + jb + jt * 16 + lo) * D_ + hi * 8;
        frag8 kh0 = *(const frag8*)(Kt + koff);
        frag8 kh1 = *(const frag8*)(Kt + koff + 32);
        frag8 kl0 = *(const frag8*)(Klo + koff);
        frag8 kl1 = *(const frag8*)(Klo + koff + 32);
#pragma unroll
        for (int q = 0; q < 2; q++) {
            f32x4 st = {0.f, 0.f, 0.f, 0.f};
            st = __builtin_amdgcn_mfma_f32_16x16x32_bf16(kh0, qfh[q][0], st, 0, 0, 0);
            st = __builtin_amdgcn_mfma_f32_16x16x32_bf16(kh1, qfh[q][1], st, 0, 0, 0);
            st = __builtin_amdgcn_mfma_f32_16x16x32_bf16(kl0, qfh[q][0], st, 0, 0, 0);
            st = __builtin_amdgcn_mfma_f32_16x16x32_bf16(kl1, qfh[q][1], st, 0, 0, 0);
            st = __builtin_amdgcn_mfma_f32_16x16x32_bf16(kh0, qfl[q][0], st, 0, 0, 0);
            st = __builtin_amdgcn_mfma_f32_16x16x32_bf16(kh1, qfl[q][1], st, 0, 0, 0);
            float p[4];
#pragma unroll
            for (int r = 0; r < 4; r++)
                p[r] = exp2f(st[r] * LOG2E - mv[q]) * lv[q];
            uint_t pk0 = (uint_t)f2bf(p[0]) | ((uint_t)f2bf(p[1]) << 16);
            uint_t pk1 = (uint_t)f2bf(p[2]) | ((uint_t)f2bf(p[3]) << 16);
            uint_t* dp = (uint_t*)&Plds[(itb + q) * 16 + lo][jt * 16 + hi * 4];
            dp[0] = pk0; dp[1] = pk1;
        }
        __syncthreads();
#pragma unroll
        for (int js = 0; js < 2; js++) {
            frag8 pa[4];
#pragma unroll
            for (int it = 0; it < 4; it++)
                pa[it] = *(const frag8*)&Plds[it * 16 + lo][js * 32 + hi * 8];
#pragma unroll
            for (int ct = 0; ct < 4; ct++) {
                frag8 vf = *(const frag8*)(Vbase + (size_t)ct * 16 * N_ + jb + js * 32 + hi * 8);
#pragma unroll
                for (int it = 0; it < 4; it++)
                    acc[it][ct] = __builtin_amdgcn_mfma_f32_16x16x32_bf16(pa[it], vf, acc[it][ct], 0, 0, 0);
            }
        }
        __syncthreads();
    }
    // D[m=i][n=c]: row i = i0+it*16+hi*4+r (4 consecutive -> f32x4 store), col c = w*64+ct*16+lo
#pragma unroll
    for (int ct = 0; ct < 4; ct++) {
#pragma unroll
        for (int it = 0; it < 4; it++) {
            float* op = out + ((size_t)b * C_ + w * 64 + ct * 16 + lo) * N_ + i0 + it * 16 + hi * 4;
            *(f32x4*)op = acc[it][ct];
        }
    }
}

extern "C" void kernel_launch(void* const* d_in, const int* in_sizes, int n_in,
                              void* d_out, int out_size, void* d_ws, size_t ws_size,
                              hipStream_t stream) {
    const float* x  = (const float*)d_in[0];
    const float* wq = (const float*)d_in[1];
    const float* bq = (const float*)d_in[2];
    const float* wk = (const float*)d_in[3];
    const float* bk = (const float*)d_in[4];
    const float* wv = (const float*)d_in[5];
    const float* bv = (const float*)d_in[6];
    float* out = (float*)d_out;

    ushort_t* xT   = (ushort_t*)d_ws;                       // B*N*C
    ushort_t* xTlo = xT + (size_t)B_ * N_ * C_;             // B*N*C
    ushort_t* Wb   = xTlo + (size_t)B_ * N_ * C_;           // 640*512
    ushort_t* Wlo  = Wb + (size_t)OROWS * 512;              // 128*512
    ushort_t* Qt   = Wlo + (size_t)128 * 512;               // B*N*64
    ushort_t* Qlo  = Qt + (size_t)B_ * N_ * D_;             // B*N*64
    ushort_t* Kt   = Qlo + (size_t)B_ * N_ * D_;            // B*N*64
    ushort_t* Klo  = Kt + (size_t)B_ * N_ * D_;             // B*N*64
    ushort_t* Vb   = Klo + (size_t)B_ * N_ * D_;            // B*C*N
    float*    m2   = (float*)(Vb + (size_t)B_ * C_ * N_);   // B*N
    float*    li   = m2 + (size_t)B_ * N_;                  // B*N

    convw<<<dim3(OROWS * 512 / (256 * 4)), 256, 0, stream>>>(wq, wk, wv, Wb, Wlo);
    xpose<<<dim3(N_ / 64, C_ / 64, B_), 256, 0, stream>>>(x, xT, xTlo);
    proj<<<dim3(N_ / 64, 10, B_), 256, 0, stream>>>(Wb, Wlo, xT, xTlo, bq, bk, bv,
                                                    Qt, Qlo, Kt, Klo, Vb);
    attn_stats<<<dim3(N_ / 64, B_), 256, 0, stream>>>(Qt, Qlo, Kt, Klo, m2, li);
    attn_out<<<dim3(B_ * N_ / 64), 512, 0, stream>>>(Qt, Qlo, Kt, Klo, Vb, m2, li, out);
}